// Round 1
// baseline (2760.707 us; speedup 1.0000x reference)
//
#include <hip/hip_runtime.h>
#include <math.h>

#define Dd 256
#define Nn 4096
#define Bb 4

// ---------------------------------------------------------------------------
// Kernel 1: QKV projection.  q[b,n,d'] = sum_d x[b,d,n] * W[d,d'] + bias[d']
// grid: (N/32, B, 3: q/k/v), block 256.
// LDS x-tile stride 260 (pad 4): keeps float4 alignment, write conflicts 4-way.
// ---------------------------------------------------------------------------
__global__ __launch_bounds__(256) void qkv_proj(
    const float* __restrict__ x,
    const float* __restrict__ Wq, const float* __restrict__ bq,
    const float* __restrict__ Wk, const float* __restrict__ bk,
    const float* __restrict__ Wv, const float* __restrict__ bv,
    float* __restrict__ Q, float* __restrict__ K, float* __restrict__ V)
{
    __shared__ __align__(16) float xs[32 * 260];
    const int t  = threadIdx.x;
    const int n0 = blockIdx.x * 32;
    const int b  = blockIdx.y;
    const int which = blockIdx.z;

    const float* W; const float* bias; float* out;
    if (which == 0)      { W = Wq; bias = bq; out = Q; }
    else if (which == 1) { W = Wk; bias = bk; out = K; }
    else                 { W = Wv; bias = bv; out = V; }

    // xs[n][d] = x[b][d][n0+n]; lanes 0..31 cover n (coalesced 128B per group)
    const float* xb = x + (size_t)b * Dd * Nn;
    const int nl = t & 31;
    const int d_base = t >> 5;
    #pragma unroll
    for (int i = 0; i < 32; ++i) {
        int d = d_base + i * 8;
        xs[nl * 260 + d] = xb[(size_t)d * Nn + n0 + nl];
    }
    __syncthreads();

    float acc[32];
    #pragma unroll
    for (int n = 0; n < 32; ++n) acc[n] = 0.f;

    // thread t owns output column d' = t
    for (int d0 = 0; d0 < Dd; d0 += 4) {
        float w0 = W[(d0 + 0) * Dd + t];
        float w1 = W[(d0 + 1) * Dd + t];
        float w2 = W[(d0 + 2) * Dd + t];
        float w3 = W[(d0 + 3) * Dd + t];
        #pragma unroll
        for (int n = 0; n < 32; ++n) {
            float4 xv = *(const float4*)&xs[n * 260 + d0];
            acc[n] = fmaf(xv.x, w0, acc[n]);
            acc[n] = fmaf(xv.y, w1, acc[n]);
            acc[n] = fmaf(xv.z, w2, acc[n]);
            acc[n] = fmaf(xv.w, w3, acc[n]);
        }
    }

    const float bv_ = bias[t];
    float* ob = out + ((size_t)b * Nn + n0) * Dd + t;
    #pragma unroll
    for (int n = 0; n < 32; ++n) ob[(size_t)n * Dd] = acc[n] + bv_;
}

// ---------------------------------------------------------------------------
// Kernel 2: flash-style attention, fp32.
// grid: (N/32, B), block 256. BQ=32 query rows per block, KV tiles of 32.
// Thread t owns output column d'=t for all 32 rows (32 fp32 accumulators),
// so the final (B,D,N) transposed store is per-thread contiguous.
// ---------------------------------------------------------------------------
__global__ __launch_bounds__(256) void attn(
    const float* __restrict__ Q, const float* __restrict__ K,
    const float* __restrict__ V, float* __restrict__ out)
{
    __shared__ __align__(16) float Qs[32 * 260];
    __shared__ __align__(16) float Ks[32 * 260];
    __shared__ __align__(16) float Vs[32 * 260];
    __shared__ __align__(16) float St[32 * 36];   // St[m][n], stride 36
    __shared__ float alpha_s[32], l_s[32], m_s[32];

    const int t  = threadIdx.x;
    const int n0 = blockIdx.x * 32;
    const int b  = blockIdx.y;

    // Load Q tile: Qs[n][d] = Q[b][n0+n][d]
    const float* Qb = Q + ((size_t)b * Nn + n0) * Dd;
    #pragma unroll
    for (int i = 0; i < 32; ++i) {
        int idx = t + i * 256;
        int d = idx & 255, n = idx >> 8;
        Qs[n * 260 + d] = Qb[idx];
    }
    if (t < 32) { l_s[t] = 0.f; m_s[t] = -1e30f; }

    float acc[32];
    #pragma unroll
    for (int n = 0; n < 32; ++n) acc[n] = 0.f;

    const float* Kb = K + (size_t)b * Nn * Dd;
    const float* Vb = V + (size_t)b * Nn * Dd;

    const int m_self = t & 31;          // S-compute: this thread's K row
    const int nq     = (t >> 5) * 4;    // S-compute: this thread's 4 Q rows

    for (int m0 = 0; m0 < Nn; m0 += 32) {
        __syncthreads();   // protect Ks/Vs/St from previous iteration's readers

        // Load K,V tiles (coalesced; LDS writes conflict-free)
        #pragma unroll
        for (int i = 0; i < 32; ++i) {
            int idx = t + i * 256;
            int d = idx & 255, m = idx >> 8;
            Ks[m * 260 + d] = Kb[(size_t)m0 * Dd + idx];
            Vs[m * 260 + d] = Vb[(size_t)m0 * Dd + idx];
        }
        __syncthreads();

        // S[n][m] = sum_d q[n][d] * k[m][d]; thread computes 4 n's x 1 m
        {
            float s0 = 0.f, s1 = 0.f, s2 = 0.f, s3 = 0.f;
            #pragma unroll 4
            for (int d0 = 0; d0 < Dd; d0 += 4) {
                float4 kv = *(const float4*)&Ks[m_self * 260 + d0];
                float4 q0 = *(const float4*)&Qs[(nq + 0) * 260 + d0];
                float4 q1 = *(const float4*)&Qs[(nq + 1) * 260 + d0];
                float4 q2 = *(const float4*)&Qs[(nq + 2) * 260 + d0];
                float4 q3 = *(const float4*)&Qs[(nq + 3) * 260 + d0];
                s0 = fmaf(q0.x, kv.x, s0); s0 = fmaf(q0.y, kv.y, s0);
                s0 = fmaf(q0.z, kv.z, s0); s0 = fmaf(q0.w, kv.w, s0);
                s1 = fmaf(q1.x, kv.x, s1); s1 = fmaf(q1.y, kv.y, s1);
                s1 = fmaf(q1.z, kv.z, s1); s1 = fmaf(q1.w, kv.w, s1);
                s2 = fmaf(q2.x, kv.x, s2); s2 = fmaf(q2.y, kv.y, s2);
                s2 = fmaf(q2.z, kv.z, s2); s2 = fmaf(q2.w, kv.w, s2);
                s3 = fmaf(q3.x, kv.x, s3); s3 = fmaf(q3.y, kv.y, s3);
                s3 = fmaf(q3.z, kv.z, s3); s3 = fmaf(q3.w, kv.w, s3);
            }
            float4 sv; sv.x = s0; sv.y = s1; sv.z = s2; sv.w = s3;
            *(float4*)&St[m_self * 36 + nq] = sv;
        }
        __syncthreads();

        // Online softmax per row; thread n<32 owns row n. St[m][n] -> p.
        if (t < 32) {
            const int n = t;
            float mx = m_s[n];
            float tmax = mx;
            #pragma unroll
            for (int m = 0; m < 32; ++m) tmax = fmaxf(tmax, St[m * 36 + n]);
            float al = __expf(mx - tmax);
            float l = l_s[n] * al;
            #pragma unroll
            for (int m = 0; m < 32; ++m) {
                float p = __expf(St[m * 36 + n] - tmax);
                St[m * 36 + n] = p;
                l += p;
            }
            m_s[n] = tmax; l_s[n] = l; alpha_s[n] = al;
        }
        __syncthreads();

        // O[n][t] = alpha*O[n][t] + sum_m p[n][m] * V[m][t]
        #pragma unroll
        for (int n = 0; n < 32; ++n) acc[n] *= alpha_s[n];
        for (int m = 0; m < 32; ++m) {
            float vv = Vs[m * 260 + t];
            #pragma unroll
            for (int n = 0; n < 32; n += 4) {
                float4 p = *(const float4*)&St[m * 36 + n];
                acc[n + 0] = fmaf(p.x, vv, acc[n + 0]);
                acc[n + 1] = fmaf(p.y, vv, acc[n + 1]);
                acc[n + 2] = fmaf(p.z, vv, acc[n + 2]);
                acc[n + 3] = fmaf(p.w, vv, acc[n + 3]);
            }
        }
    }

    // Write out[b][t][n0+n] = acc[n] / l[n]; per-thread contiguous 128B.
    float* ob = out + ((size_t)b * Dd + t) * Nn + n0;
    #pragma unroll
    for (int n = 0; n < 32; n += 4) {
        float4 o;
        o.x = acc[n + 0] / l_s[n + 0];
        o.y = acc[n + 1] / l_s[n + 1];
        o.z = acc[n + 2] / l_s[n + 2];
        o.w = acc[n + 3] / l_s[n + 3];
        *(float4*)&ob[n] = o;
    }
}

extern "C" void kernel_launch(void* const* d_in, const int* in_sizes, int n_in,
                              void* d_out, int out_size, void* d_ws, size_t ws_size,
                              hipStream_t stream) {
    const float* x  = (const float*)d_in[0];
    const float* Wq = (const float*)d_in[1];
    const float* bq = (const float*)d_in[2];
    const float* Wk = (const float*)d_in[3];
    const float* bk = (const float*)d_in[4];
    const float* Wv = (const float*)d_in[5];
    const float* bv = (const float*)d_in[6];
    float* out = (float*)d_out;

    // Workspace: Q, K, V each B*N*D fp32 = 16 MB (48 MB total)
    float* Q = (float*)d_ws;
    float* K = Q + (size_t)Bb * Nn * Dd;
    float* V = K + (size_t)Bb * Nn * Dd;

    qkv_proj<<<dim3(Nn / 32, Bb, 3), 256, 0, stream>>>(x, Wq, bq, Wk, bk, Wv, bv, Q, K, V);
    attn<<<dim3(Nn / 32, Bb), 256, 0, stream>>>(Q, K, V, out);
}

// Round 2
// 448.636 us; speedup vs baseline: 6.1536x; 6.1536x over previous
//
#include <hip/hip_runtime.h>
#include <math.h>

#define Dd 256
#define Nn 4096
#define Bb 4
#define BQ 64     // q rows per attn block (4 waves x 16)
#define BK 32     // kv rows per tile

typedef _Float16 f16;
typedef _Float16 half8 __attribute__((ext_vector_type(8)));
typedef float f32x4 __attribute__((ext_vector_type(4)));

// ---------------------------------------------------------------------------
// Kernel 1: QKV projection (fp32 math, fp16 outputs).
//   Q,K written (B,N,D) fp16 row-major; V written TRANSPOSED (B,D,N) fp16 so
//   the attention kernel's PV B-fragments are contiguous in LDS.
// grid: (N/32, B, 3), block 256. Thread t owns output column d'=t.
// ---------------------------------------------------------------------------
__global__ __launch_bounds__(256) void qkv_proj(
    const float* __restrict__ x,
    const float* __restrict__ Wq, const float* __restrict__ bq,
    const float* __restrict__ Wk, const float* __restrict__ bk,
    const float* __restrict__ Wv, const float* __restrict__ bv,
    f16* __restrict__ Qh, f16* __restrict__ Kh, f16* __restrict__ Vth)
{
    __shared__ __align__(16) float xs[32 * 260];
    const int t  = threadIdx.x;
    const int n0 = blockIdx.x * 32;
    const int b  = blockIdx.y;
    const int which = blockIdx.z;

    const float* W; const float* bias;
    if (which == 0)      { W = Wq; bias = bq; }
    else if (which == 1) { W = Wk; bias = bk; }
    else                 { W = Wv; bias = bv; }

    // xs[n][d] = x[b][d][n0+n]
    const float* xb = x + (size_t)b * Dd * Nn;
    const int nl = t & 31;
    const int d_base = t >> 5;
    #pragma unroll
    for (int i = 0; i < 32; ++i) {
        int d = d_base + i * 8;
        xs[nl * 260 + d] = xb[(size_t)d * Nn + n0 + nl];
    }
    __syncthreads();

    float acc[32];
    #pragma unroll
    for (int n = 0; n < 32; ++n) acc[n] = 0.f;

    for (int d0 = 0; d0 < Dd; d0 += 4) {
        float w0 = W[(d0 + 0) * Dd + t];
        float w1 = W[(d0 + 1) * Dd + t];
        float w2 = W[(d0 + 2) * Dd + t];
        float w3 = W[(d0 + 3) * Dd + t];
        #pragma unroll
        for (int n = 0; n < 32; ++n) {
            float4 xv = *(const float4*)&xs[n * 260 + d0];
            acc[n] = fmaf(xv.x, w0, acc[n]);
            acc[n] = fmaf(xv.y, w1, acc[n]);
            acc[n] = fmaf(xv.z, w2, acc[n]);
            acc[n] = fmaf(xv.w, w3, acc[n]);
        }
    }

    const float bv_ = bias[t];
    if (which < 2) {
        f16* ob = (which == 0 ? Qh : Kh) + ((size_t)b * Nn + n0) * Dd + t;
        #pragma unroll
        for (int n = 0; n < 32; ++n) ob[(size_t)n * Dd] = (f16)(acc[n] + bv_);
    } else {
        // V transposed: Vth[b][d'=t][n0..n0+31], per-thread contiguous 64 B
        f16 buf[32];
        #pragma unroll
        for (int n = 0; n < 32; ++n) buf[n] = (f16)(acc[n] + bv_);
        f16* ob = Vth + ((size_t)b * Dd + t) * Nn + n0;
        #pragma unroll
        for (int i = 0; i < 4; ++i)
            *(half8*)(ob + i * 8) = *(const half8*)&buf[i * 8];
    }
}

// ---------------------------------------------------------------------------
// Kernel 2: MFMA flash attention.
// grid (N/64, B), block 256 = 4 waves; wave w owns q rows [q0+16w, q0+16w+16).
// Q fragments register-resident; K,V^T tiles (BK=32) staged in LDS;
// P converted C-layout -> A-layout via per-wave LDS round-trip.
// All LDS row strides are multiples of 16 B; worst aliasing 2-way (free).
// ---------------------------------------------------------------------------
__global__ __launch_bounds__(256) void attn_mfma(
    const f16* __restrict__ Qh, const f16* __restrict__ Kh,
    const f16* __restrict__ Vth, float* __restrict__ out)
{
    __shared__ f16 Ks[BK][264];       // 16.9 KB  K[kv][d], pad 8
    __shared__ f16 Vts[Dd][40];       // 20.5 KB  V^T[d][kv], pad 8
    __shared__ f16 Ps[4][16][40];     //  5.1 KB  per-wave P[q][kv], pad 8

    const int t    = threadIdx.x;
    const int wave = t >> 6, lane = t & 63;
    const int quad = lane >> 4, l15 = lane & 15;
    const int b    = blockIdx.y;
    const int q0   = blockIdx.x * BQ;
    const int qw   = q0 + wave * 16;

    // Q A-fragments: qf[c] holds Q[qw+l15][c*32 + quad*8 + j], j=0..7
    half8 qf[8];
    const f16* Qrow = Qh + ((size_t)b * Nn + qw + l15) * Dd + quad * 8;
    #pragma unroll
    for (int c = 0; c < 8; ++c) qf[c] = *(const half8*)(Qrow + c * 32);

    f32x4 acc[16];
    #pragma unroll
    for (int n = 0; n < 16; ++n) acc[n] = (f32x4){0.f, 0.f, 0.f, 0.f};
    f32x4 m4 = {-1e30f, -1e30f, -1e30f, -1e30f};
    f32x4 l4 = {0.f, 0.f, 0.f, 0.f};

    const f16* Kb = Kh  + (size_t)b * Nn * Dd;
    const f16* Vb = Vth + (size_t)b * Dd * Nn;

    for (int k0 = 0; k0 < Nn; k0 += BK) {
        __syncthreads();   // prior-iter LDS readers done before restage

        // Stage K tile: 32 rows x 256 halfs (coalesced 512B runs)
        #pragma unroll
        for (int i = 0; i < 4; ++i) {
            int u = t + i * 256;
            int r = u >> 5, c = u & 31;
            *(half8*)&Ks[r][c * 8] =
                *(const half8*)(Kb + (size_t)(k0 + r) * Dd + c * 8);
        }
        // Stage V^T tile: 256 rows x 32 halfs
        #pragma unroll
        for (int i = 0; i < 4; ++i) {
            int u = t + i * 256;
            int d = u >> 2, c = u & 3;
            *(half8*)&Vts[d][c * 8] =
                *(const half8*)(Vb + (size_t)d * Nn + k0 + c * 8);
        }
        __syncthreads();

        // S = Q K^T : two 16x16 S-blocks (kv cols 0-15, 16-31)
        f32x4 S0 = {0.f, 0.f, 0.f, 0.f}, S1 = {0.f, 0.f, 0.f, 0.f};
        #pragma unroll
        for (int c = 0; c < 8; ++c) {
            half8 kb0 = *(const half8*)&Ks[l15][c * 32 + quad * 8];
            half8 kb1 = *(const half8*)&Ks[16 + l15][c * 32 + quad * 8];
            S0 = __builtin_amdgcn_mfma_f32_16x16x32_f16(qf[c], kb0, S0, 0, 0, 0);
            S1 = __builtin_amdgcn_mfma_f32_16x16x32_f16(qf[c], kb1, S1, 0, 0, 0);
        }

        // Online softmax. C-layout: row q = quad*4 + reg, col kv = sblk*16+l15.
        f32x4 tmax;
        tmax.x = fmaxf(S0.x, S1.x); tmax.y = fmaxf(S0.y, S1.y);
        tmax.z = fmaxf(S0.z, S1.z); tmax.w = fmaxf(S0.w, S1.w);
        #pragma unroll
        for (int off = 1; off < 16; off <<= 1) {
            tmax.x = fmaxf(tmax.x, __shfl_xor(tmax.x, off));
            tmax.y = fmaxf(tmax.y, __shfl_xor(tmax.y, off));
            tmax.z = fmaxf(tmax.z, __shfl_xor(tmax.z, off));
            tmax.w = fmaxf(tmax.w, __shfl_xor(tmax.w, off));
        }
        f32x4 newm;
        newm.x = fmaxf(m4.x, tmax.x); newm.y = fmaxf(m4.y, tmax.y);
        newm.z = fmaxf(m4.z, tmax.z); newm.w = fmaxf(m4.w, tmax.w);
        f32x4 al;
        al.x = __expf(m4.x - newm.x); al.y = __expf(m4.y - newm.y);
        al.z = __expf(m4.z - newm.z); al.w = __expf(m4.w - newm.w);
        f32x4 P0, P1;
        P0.x = __expf(S0.x - newm.x); P0.y = __expf(S0.y - newm.y);
        P0.z = __expf(S0.z - newm.z); P0.w = __expf(S0.w - newm.w);
        P1.x = __expf(S1.x - newm.x); P1.y = __expf(S1.y - newm.y);
        P1.z = __expf(S1.z - newm.z); P1.w = __expf(S1.w - newm.w);
        f32x4 rsum = P0 + P1;
        #pragma unroll
        for (int off = 1; off < 16; off <<= 1) {
            rsum.x += __shfl_xor(rsum.x, off);
            rsum.y += __shfl_xor(rsum.y, off);
            rsum.z += __shfl_xor(rsum.z, off);
            rsum.w += __shfl_xor(rsum.w, off);
        }
        l4 = l4 * al + rsum;
        m4 = newm;

        // Rescale O unless the running max didn't move (common after warm-up)
        int need = (al.x != 1.f) | (al.y != 1.f) | (al.z != 1.f) | (al.w != 1.f);
        if (__any(need)) {
            #pragma unroll
            for (int n = 0; n < 16; ++n) acc[n] *= al;
        }

        // P: C-layout -> LDS (A-layout read below). 8 scalar b16 writes.
        const int pr = quad * 4;
        Ps[wave][pr + 0][l15] = (f16)P0.x;
        Ps[wave][pr + 1][l15] = (f16)P0.y;
        Ps[wave][pr + 2][l15] = (f16)P0.z;
        Ps[wave][pr + 3][l15] = (f16)P0.w;
        Ps[wave][pr + 0][16 + l15] = (f16)P1.x;
        Ps[wave][pr + 1][16 + l15] = (f16)P1.y;
        Ps[wave][pr + 2][16 + l15] = (f16)P1.z;
        Ps[wave][pr + 3][16 + l15] = (f16)P1.w;
        // same-wave write->read: ordered by lgkmcnt, no block barrier needed

        // O += P V : A-frag = P[q=l15][kv=quad*8+j], B-frag = V^T[d][kv]
        half8 ap = *(const half8*)&Ps[wave][l15][quad * 8];
        #pragma unroll
        for (int nb = 0; nb < 16; ++nb) {
            half8 vb = *(const half8*)&Vts[nb * 16 + l15][quad * 8];
            acc[nb] = __builtin_amdgcn_mfma_f32_16x16x32_f16(ap, vb, acc[nb], 0, 0, 0);
        }
    }

    // Epilogue: out[b][d][n] = O[q][d]/l ; float4 per lane, 64B-coalesced rows
    f32x4 inv;
    inv.x = 1.f / l4.x; inv.y = 1.f / l4.y;
    inv.z = 1.f / l4.z; inv.w = 1.f / l4.w;
    #pragma unroll
    for (int nb = 0; nb < 16; ++nb) {
        int d = nb * 16 + l15;
        f32x4 o = acc[nb] * inv;
        float* p = out + ((size_t)b * Dd + d) * Nn + qw + quad * 4;
        *(f32x4*)p = o;
    }
}

extern "C" void kernel_launch(void* const* d_in, const int* in_sizes, int n_in,
                              void* d_out, int out_size, void* d_ws, size_t ws_size,
                              hipStream_t stream) {
    const float* x  = (const float*)d_in[0];
    const float* Wq = (const float*)d_in[1];
    const float* bq = (const float*)d_in[2];
    const float* Wk = (const float*)d_in[3];
    const float* bk = (const float*)d_in[4];
    const float* Wv = (const float*)d_in[5];
    const float* bv = (const float*)d_in[6];
    float* out = (float*)d_out;

    // ws: Qh (8MB) | Kh (8MB) | Vth (8MB), all fp16
    f16* Qh  = (f16*)d_ws;
    f16* Kh  = Qh + (size_t)Bb * Nn * Dd;
    f16* Vth = Kh + (size_t)Bb * Nn * Dd;

    qkv_proj<<<dim3(Nn / 32, Bb, 3), 256, 0, stream>>>(
        x, Wq, bq, Wk, bk, Wv, bv, Qh, Kh, Vth);
    attn_mfma<<<dim3(Nn / BQ, Bb), 256, 0, stream>>>(Qh, Kh, Vth, out);
}

// Round 3
// 374.550 us; speedup vs baseline: 7.3707x; 1.1978x over previous
//
#include <hip/hip_runtime.h>
#include <math.h>

#define Dd 256
#define Nn 4096
#define Bb 4
#define BQ 64       // q rows per attn block (4 waves x 16)
#define BK 32       // kv rows per tile
#define SPLIT 4     // KV splits (flash-decode style)

typedef _Float16 f16;
typedef _Float16 half8 __attribute__((ext_vector_type(8)));
typedef _Float16 half4 __attribute__((ext_vector_type(4)));
typedef float f32x4 __attribute__((ext_vector_type(4)));

// ---------------------------------------------------------------------------
// Kernel 0: W transpose+cast.  Wt[which][d'][d] = (f16) W[d][d']
// grid (16, 3), block 256. 64x64 tiles via LDS.
// ---------------------------------------------------------------------------
__global__ __launch_bounds__(256) void wtrans(
    const float* __restrict__ Wq, const float* __restrict__ Wk,
    const float* __restrict__ Wv, f16* __restrict__ Wt)
{
    __shared__ float ld[64][65];
    const int which = blockIdx.y;
    const float* W = which == 0 ? Wq : (which == 1 ? Wk : Wv);
    const int tr = (blockIdx.x >> 2) * 64;   // d tile
    const int tc = (blockIdx.x & 3) * 64;    // d' tile
    const int t = threadIdx.x;
    #pragma unroll
    for (int i = 0; i < 16; ++i) {
        int u = t + i * 256, r = u >> 6, c = u & 63;
        ld[r][c] = W[(size_t)(tr + r) * Dd + tc + c];
    }
    __syncthreads();
    f16* Wo = Wt + (size_t)which * Dd * Dd;
    #pragma unroll
    for (int i = 0; i < 16; ++i) {
        int u = t + i * 256, cp = u >> 6, rp = u & 63;
        Wo[(size_t)(tc + cp) * Dd + tr + rp] = (f16)ld[rp][cp];
    }
}

// ---------------------------------------------------------------------------
// Kernel 1: QKV projection via MFMA.
// C[n][d'] = sum_d xT[n][d] * Wt[d'][d]  (+bias).  fp16 inputs, fp32 acc.
// grid (N/64, B, 3), block 256 (4 waves; wave w owns rows 16w..16w+16).
// Q,K out (B,N,D) f16; V out transposed (B,D,N) f16.
// ---------------------------------------------------------------------------
__global__ __launch_bounds__(256, 2) void qkv_mfma(
    const float* __restrict__ x, const f16* __restrict__ Wt,
    const float* __restrict__ bq, const float* __restrict__ bk,
    const float* __restrict__ bv,
    f16* __restrict__ Qh, f16* __restrict__ Kh, f16* __restrict__ Vth)
{
    __shared__ f16 xT[64][264];     // 33.8 KB, x^T tile (n, d), pad 8
    __shared__ f16 Wls[256][40];    // 20.5 KB, W^T chunk (d', 32 d), pad 8
    __shared__ float bs[256];
    const int t = threadIdx.x;
    const int wave = t >> 6, lane = t & 63, quad = lane >> 4, l15 = lane & 15;
    const int n0 = blockIdx.x * 64;
    const int b = blockIdx.y, which = blockIdx.z;
    const float* bias = which == 0 ? bq : (which == 1 ? bk : bv);
    bs[t] = bias[t];

    // Stage x^T tile: read x (B,D,N) fp32 coalesced along n, write f16 transposed
    const float* xb = x + (size_t)b * Dd * Nn;
    #pragma unroll
    for (int i = 0; i < 16; ++i) {
        int u = t + i * 256, d = u >> 4, nq = (u & 15) * 4;
        float4 v4 = *(const float4*)&xb[(size_t)d * Nn + n0 + nq];
        xT[nq + 0][d] = (f16)v4.x; xT[nq + 1][d] = (f16)v4.y;
        xT[nq + 2][d] = (f16)v4.z; xT[nq + 3][d] = (f16)v4.w;
    }
    __syncthreads();

    // A-fragments (register resident): a[c] = xT[16w+l15][c*32 + quad*8 ..+8]
    half8 a[8];
    #pragma unroll
    for (int c = 0; c < 8; ++c)
        a[c] = *(const half8*)&xT[16 * wave + l15][c * 32 + quad * 8];

    f32x4 acc[16];
    #pragma unroll
    for (int dt = 0; dt < 16; ++dt) acc[dt] = (f32x4){0.f, 0.f, 0.f, 0.f};

    const f16* Wb = Wt + (size_t)which * Dd * Dd;
    for (int c = 0; c < 8; ++c) {
        __syncthreads();   // prior chunk consumed
        #pragma unroll
        for (int j = 0; j < 4; ++j) {
            int u = t + j * 256, dp = u >> 2, p = u & 3;
            *(half8*)&Wls[dp][p * 8] =
                *(const half8*)(Wb + (size_t)dp * Dd + c * 32 + p * 8);
        }
        __syncthreads();
        #pragma unroll
        for (int dt = 0; dt < 16; ++dt) {
            half8 bfr = *(const half8*)&Wls[dt * 16 + l15][quad * 8];
            acc[dt] = __builtin_amdgcn_mfma_f32_16x16x32_f16(a[c], bfr, acc[dt], 0, 0, 0);
        }
    }

    // Epilogue. C layout: row n = quad*4+reg, col d' = dt*16 + l15
    const int nrow = n0 + 16 * wave + quad * 4;
    if (which < 2) {
        f16* O = (which == 0 ? Qh : Kh) + ((size_t)b * Nn + nrow) * Dd;
        #pragma unroll
        for (int dt = 0; dt < 16; ++dt) {
            int col = dt * 16 + l15;
            float bvv = bs[col];
            #pragma unroll
            for (int r = 0; r < 4; ++r)
                O[(size_t)r * Dd + col] = (f16)(acc[dt][r] + bvv);
        }
    } else {
        f16* O = Vth + (size_t)b * Dd * Nn;   // (d', n)
        #pragma unroll
        for (int dt = 0; dt < 16; ++dt) {
            int col = dt * 16 + l15;
            float bvv = bs[col];
            half4 o;
            #pragma unroll
            for (int r = 0; r < 4; ++r) o[r] = (f16)(acc[dt][r] + bvv);
            *(half4*)&O[(size_t)col * Nn + nrow] = o;
        }
    }
}

// ---------------------------------------------------------------------------
// Kernel 2: MFMA flash attention, split-KV.
// grid (N/64, B, SPLIT), block 256. Each block: 64 q rows x 1024 kv rows.
// Writes normalized partial O (f16, (S,B,D,N)) + m,l per row.
// LDS 39936 B -> 4 blocks/CU -> 4 waves/SIMD.
// ---------------------------------------------------------------------------
__global__ __launch_bounds__(256, 4) void attn_mfma(
    const f16* __restrict__ Qh, const f16* __restrict__ Kh,
    const f16* __restrict__ Vth, f16* __restrict__ Opart,
    float* __restrict__ mpart, float* __restrict__ lpart)
{
    __shared__ f16 Ks[BK][264];       // 16896 B  K[kv][d], pad 8 (b128-aligned)
    __shared__ f16 Vts[Dd][36];       // 18432 B  V^T[d][kv], pad 4 (b64 reads)
    __shared__ f16 Ps[4][16][36];     //  4608 B  per-wave P[q][kv], pad 4

    const int t    = threadIdx.x;
    const int wave = t >> 6, lane = t & 63;
    const int quad = lane >> 4, l15 = lane & 15;
    const int b    = blockIdx.y;
    const int s    = blockIdx.z;
    const int q0   = blockIdx.x * BQ;
    const int qw   = q0 + wave * 16;
    const int kv0  = s * (Nn / SPLIT);

    half8 qf[8];
    const f16* Qrow = Qh + ((size_t)b * Nn + qw + l15) * Dd + quad * 8;
    #pragma unroll
    for (int c = 0; c < 8; ++c) qf[c] = *(const half8*)(Qrow + c * 32);

    f32x4 acc[16];
    #pragma unroll
    for (int n = 0; n < 16; ++n) acc[n] = (f32x4){0.f, 0.f, 0.f, 0.f};
    f32x4 m4 = {-1e30f, -1e30f, -1e30f, -1e30f};
    f32x4 l4 = {0.f, 0.f, 0.f, 0.f};

    const f16* Kb = Kh  + (size_t)b * Nn * Dd;
    const f16* Vb = Vth + (size_t)b * Dd * Nn;

    for (int k0 = kv0; k0 < kv0 + Nn / SPLIT; k0 += BK) {
        __syncthreads();

        #pragma unroll
        for (int i = 0; i < 4; ++i) {
            int u = t + i * 256;
            int r = u >> 5, c = u & 31;
            *(half8*)&Ks[r][c * 8] =
                *(const half8*)(Kb + (size_t)(k0 + r) * Dd + c * 8);
        }
        #pragma unroll
        for (int i = 0; i < 4; ++i) {
            int u = t + i * 256;
            int d = u >> 2, c = u & 3;
            half8 v8 = *(const half8*)(Vb + (size_t)d * Nn + k0 + c * 8);
            // row stride 72 B: b64 stores (8B-aligned)
            half4 vlo = {v8[0], v8[1], v8[2], v8[3]};
            half4 vhi = {v8[4], v8[5], v8[6], v8[7]};
            *(half4*)&Vts[d][c * 8]     = vlo;
            *(half4*)&Vts[d][c * 8 + 4] = vhi;
        }
        __syncthreads();

        f32x4 S0 = {0.f, 0.f, 0.f, 0.f}, S1 = {0.f, 0.f, 0.f, 0.f};
        #pragma unroll
        for (int c = 0; c < 8; ++c) {
            half8 kb0 = *(const half8*)&Ks[l15][c * 32 + quad * 8];
            half8 kb1 = *(const half8*)&Ks[16 + l15][c * 32 + quad * 8];
            S0 = __builtin_amdgcn_mfma_f32_16x16x32_f16(qf[c], kb0, S0, 0, 0, 0);
            S1 = __builtin_amdgcn_mfma_f32_16x16x32_f16(qf[c], kb1, S1, 0, 0, 0);
        }

        f32x4 tmax;
        tmax.x = fmaxf(S0.x, S1.x); tmax.y = fmaxf(S0.y, S1.y);
        tmax.z = fmaxf(S0.z, S1.z); tmax.w = fmaxf(S0.w, S1.w);
        #pragma unroll
        for (int off = 1; off < 16; off <<= 1) {
            tmax.x = fmaxf(tmax.x, __shfl_xor(tmax.x, off));
            tmax.y = fmaxf(tmax.y, __shfl_xor(tmax.y, off));
            tmax.z = fmaxf(tmax.z, __shfl_xor(tmax.z, off));
            tmax.w = fmaxf(tmax.w, __shfl_xor(tmax.w, off));
        }
        f32x4 newm;
        newm.x = fmaxf(m4.x, tmax.x); newm.y = fmaxf(m4.y, tmax.y);
        newm.z = fmaxf(m4.z, tmax.z); newm.w = fmaxf(m4.w, tmax.w);
        f32x4 al;
        al.x = __expf(m4.x - newm.x); al.y = __expf(m4.y - newm.y);
        al.z = __expf(m4.z - newm.z); al.w = __expf(m4.w - newm.w);
        f32x4 P0, P1;
        P0.x = __expf(S0.x - newm.x); P0.y = __expf(S0.y - newm.y);
        P0.z = __expf(S0.z - newm.z); P0.w = __expf(S0.w - newm.w);
        P1.x = __expf(S1.x - newm.x); P1.y = __expf(S1.y - newm.y);
        P1.z = __expf(S1.z - newm.z); P1.w = __expf(S1.w - newm.w);
        f32x4 rsum = P0 + P1;
        #pragma unroll
        for (int off = 1; off < 16; off <<= 1) {
            rsum.x += __shfl_xor(rsum.x, off);
            rsum.y += __shfl_xor(rsum.y, off);
            rsum.z += __shfl_xor(rsum.z, off);
            rsum.w += __shfl_xor(rsum.w, off);
        }
        l4 = l4 * al + rsum;
        m4 = newm;

        int need = (al.x != 1.f) | (al.y != 1.f) | (al.z != 1.f) | (al.w != 1.f);
        if (__any(need)) {
            #pragma unroll
            for (int n = 0; n < 16; ++n) acc[n] *= al;
        }

        const int pr = quad * 4;
        Ps[wave][pr + 0][l15] = (f16)P0.x;
        Ps[wave][pr + 1][l15] = (f16)P0.y;
        Ps[wave][pr + 2][l15] = (f16)P0.z;
        Ps[wave][pr + 3][l15] = (f16)P0.w;
        Ps[wave][pr + 0][16 + l15] = (f16)P1.x;
        Ps[wave][pr + 1][16 + l15] = (f16)P1.y;
        Ps[wave][pr + 2][16 + l15] = (f16)P1.z;
        Ps[wave][pr + 3][16 + l15] = (f16)P1.w;

        half4 alo = *(const half4*)&Ps[wave][l15][quad * 8];
        half4 ahi = *(const half4*)&Ps[wave][l15][quad * 8 + 4];
        half8 ap = __builtin_shufflevector(alo, ahi, 0, 1, 2, 3, 4, 5, 6, 7);
        #pragma unroll
        for (int nb = 0; nb < 16; ++nb) {
            half4 vlo = *(const half4*)&Vts[nb * 16 + l15][quad * 8];
            half4 vhi = *(const half4*)&Vts[nb * 16 + l15][quad * 8 + 4];
            half8 vb = __builtin_shufflevector(vlo, vhi, 0, 1, 2, 3, 4, 5, 6, 7);
            acc[nb] = __builtin_amdgcn_mfma_f32_16x16x32_f16(ap, vb, acc[nb], 0, 0, 0);
        }
    }

    // Epilogue: normalized partial O (f16) + m,l
    f32x4 inv;
    inv.x = 1.f / l4.x; inv.y = 1.f / l4.y;
    inv.z = 1.f / l4.z; inv.w = 1.f / l4.w;
    f16* Ob = Opart + ((size_t)(s * Bb + b) * Dd) * Nn;
    #pragma unroll
    for (int nb = 0; nb < 16; ++nb) {
        int d = nb * 16 + l15;
        half4 o;
        o[0] = (f16)(acc[nb][0] * inv.x);
        o[1] = (f16)(acc[nb][1] * inv.y);
        o[2] = (f16)(acc[nb][2] * inv.z);
        o[3] = (f16)(acc[nb][3] * inv.w);
        *(half4*)&Ob[(size_t)d * Nn + qw + quad * 4] = o;
    }
    if (l15 == 0) {
        float mv[4] = {m4.x, m4.y, m4.z, m4.w};
        float lv[4] = {l4.x, l4.y, l4.z, l4.w};
        #pragma unroll
        for (int r = 0; r < 4; ++r) {
            int n = qw + quad * 4 + r;
            mpart[(size_t)(s * Bb + b) * Nn + n] = mv[r];
            lpart[(size_t)(s * Bb + b) * Nn + n] = lv[r];
        }
    }
}

// ---------------------------------------------------------------------------
// Kernel 3: combine split partials.
// out[b][d][n] = sum_s w_s(b,n) * Opart[s][b][d][n],
//   w_s = l_s exp(m_s - M) / sum_s l_s exp(m_s - M)
// grid (N/2048, D, B), block 256; thread handles 8 consecutive n.
// ---------------------------------------------------------------------------
__global__ __launch_bounds__(256) void combine(
    const f16* __restrict__ Opart, const float* __restrict__ mpart,
    const float* __restrict__ lpart, float* __restrict__ out)
{
    const int t = threadIdx.x;
    const int n0 = (blockIdx.x * 256 + t) * 8;
    const int d = blockIdx.y, b = blockIdx.z;

    float m[SPLIT][8], l[SPLIT][8];
    #pragma unroll
    for (int s = 0; s < SPLIT; ++s) {
        size_t base = (size_t)(s * Bb + b) * Nn + n0;
        float4 a0 = *(const float4*)&mpart[base];
        float4 a1 = *(const float4*)&mpart[base + 4];
        float4 c0 = *(const float4*)&lpart[base];
        float4 c1 = *(const float4*)&lpart[base + 4];
        m[s][0]=a0.x; m[s][1]=a0.y; m[s][2]=a0.z; m[s][3]=a0.w;
        m[s][4]=a1.x; m[s][5]=a1.y; m[s][6]=a1.z; m[s][7]=a1.w;
        l[s][0]=c0.x; l[s][1]=c0.y; l[s][2]=c0.z; l[s][3]=c0.w;
        l[s][4]=c1.x; l[s][5]=c1.y; l[s][6]=c1.z; l[s][7]=c1.w;
    }
    float w[SPLIT][8];
    #pragma unroll
    for (int j = 0; j < 8; ++j) {
        float M = m[0][j];
        #pragma unroll
        for (int s = 1; s < SPLIT; ++s) M = fmaxf(M, m[s][j]);
        float L = 0.f;
        #pragma unroll
        for (int s = 0; s < SPLIT; ++s) {
            float ws = l[s][j] * __expf(m[s][j] - M);
            w[s][j] = ws; L += ws;
        }
        float invL = 1.f / L;
        #pragma unroll
        for (int s = 0; s < SPLIT; ++s) w[s][j] *= invL;
    }

    float o[8];
    #pragma unroll
    for (int j = 0; j < 8; ++j) o[j] = 0.f;
    #pragma unroll
    for (int s = 0; s < SPLIT; ++s) {
        half8 h = *(const half8*)&Opart[((size_t)(s * Bb + b) * Dd + d) * Nn + n0];
        #pragma unroll
        for (int j = 0; j < 8; ++j) o[j] += w[s][j] * (float)h[j];
    }
    float* op = out + ((size_t)b * Dd + d) * Nn + n0;
    f32x4 o0 = {o[0], o[1], o[2], o[3]};
    f32x4 o1 = {o[4], o[5], o[6], o[7]};
    *(f32x4*)op = o0;
    *(f32x4*)(op + 4) = o1;
}

extern "C" void kernel_launch(void* const* d_in, const int* in_sizes, int n_in,
                              void* d_out, int out_size, void* d_ws, size_t ws_size,
                              hipStream_t stream) {
    const float* x  = (const float*)d_in[0];
    const float* Wq = (const float*)d_in[1];
    const float* bq = (const float*)d_in[2];
    const float* Wk = (const float*)d_in[3];
    const float* bk = (const float*)d_in[4];
    const float* Wv = (const float*)d_in[5];
    const float* bv = (const float*)d_in[6];
    float* out = (float*)d_out;

    // ws layout (f16 unless noted):
    // Qh 8MB | Kh 8MB | Vth 8MB | Wt 384KB | Opart 33.5MB | mpart,lpart f32 256KB each
    f16* Qh    = (f16*)d_ws;
    f16* Kh    = Qh + (size_t)Bb * Nn * Dd;
    f16* Vth   = Kh + (size_t)Bb * Nn * Dd;
    f16* Wt    = Vth + (size_t)Bb * Nn * Dd;
    f16* Opart = Wt + (size_t)3 * Dd * Dd;
    float* mpart = (float*)(Opart + (size_t)SPLIT * Bb * Dd * Nn);
    float* lpart = mpart + (size_t)SPLIT * Bb * Nn;

    wtrans<<<dim3(16, 3), 256, 0, stream>>>(Wq, Wk, Wv, Wt);
    qkv_mfma<<<dim3(Nn / 64, Bb, 3), 256, 0, stream>>>(
        x, Wt, bq, bk, bv, Qh, Kh, Vth);
    attn_mfma<<<dim3(Nn / BQ, Bb, SPLIT), 256, 0, stream>>>(
        Qh, Kh, Vth, Opart, mpart, lpart);
    combine<<<dim3(Nn / 2048, Dd, Bb), 256, 0, stream>>>(
        Opart, mpart, lpart, out);
}